// Round 1
// baseline (354.199 us; speedup 1.0000x reference)
//
#include <hip/hip_runtime.h>
#include <math.h>

// ListMLE loss: B=8192 rows, L=2048 cols.
// loss = mean_over_rows( sum_i [ LSE(s_sorted[i:]) - s_sorted[i] ] )
// where s_sorted = scores gathered by argsort(-labels) (stable).

constexpr int L = 2048;
constexpr int T = 256;          // threads per block
constexpr int C = L / T;        // 8 elements per thread in the scan phase

// Order-preserving float32 -> uint32 transform (unsigned compare == float compare).
__device__ inline unsigned keyxform(float f) {
    unsigned u = __float_as_uint(f);
    return (u & 0x80000000u) ? ~u : (u | 0x80000000u);
}

__global__ __launch_bounds__(T) void listmle_row_kernel(
        const float* __restrict__ scores,
        const float* __restrict__ labels,
        float* __restrict__ row_loss) {
    __shared__ unsigned long long keys[L];  // 16 KB
    __shared__ float sc[L];                 // 8 KB
    __shared__ float sm[T];                 // 1 KB
    __shared__ float se[T];                 // 1 KB

    const int row = blockIdx.x;
    const int tid = threadIdx.x;
    const long long base = (long long)row * L;

    // ---- load row: key = (xform(label) << 32) | ~idx  (desc sort => label desc, idx asc) ----
    for (int i = tid; i < L; i += T) {
        float lab = labels[base + i];
        keys[i] = ((unsigned long long)keyxform(lab) << 32) | (unsigned)(~i);
        sc[i] = scores[base + i];
    }
    __syncthreads();

    // ---- bitonic sort, descending ----
    for (int k = 2; k <= L; k <<= 1) {
        for (int j = k >> 1; j > 0; j >>= 1) {
            #pragma unroll
            for (int t = tid; t < L / 2; t += T) {
                const int i0 = ((t & ~(j - 1)) << 1) | (t & (j - 1));
                const int i1 = i0 | j;
                const unsigned long long a = keys[i0];
                const unsigned long long b = keys[i1];
                const bool desc = ((i0 & k) == 0);
                if (desc ? (a < b) : (a > b)) {
                    keys[i0] = b;
                    keys[i1] = a;
                }
            }
            __syncthreads();
        }
    }

    // ---- gather scores in sorted order: thread tid owns slots [tid*C, tid*C+C) ----
    float x[C];
    #pragma unroll
    for (int c = 0; c < C; ++c) {
        const unsigned long long kk = keys[tid * C + c];
        const int idx = (int)(~(unsigned)kk);   // recover original column index
        x[c] = sc[idx];
    }

    // ---- per-thread chunk LSE aggregate (m, e) with e = sum exp(x - m) ----
    float m = x[0], e = 1.0f;
    #pragma unroll
    for (int c = 1; c < C; ++c) {
        const float xv = x[c];
        if (xv > m) { e = e * __expf(m - xv) + 1.0f; m = xv; }
        else        { e += __expf(xv - m); }
    }

    // ---- inclusive suffix scan of (m, e) pairs across the 256 threads ----
    sm[tid] = m;
    se[tid] = e;
    __syncthreads();
    for (int off = 1; off < T; off <<= 1) {
        float m2 = -INFINITY, e2 = 0.0f;
        if (tid + off < T) { m2 = sm[tid + off]; e2 = se[tid + off]; }
        __syncthreads();
        const float mm = sm[tid], ee = se[tid];
        const float M = fmaxf(mm, m2);
        const float E = ee * __expf(mm - M) + e2 * __expf(m2 - M);
        sm[tid] = M;
        se[tid] = E;
        __syncthreads();
    }

    // exclusive suffix aggregate for this thread = inclusive at tid+1
    const float Ms0 = (tid + 1 < T) ? sm[tid + 1] : -INFINITY;
    const float Es0 = (tid + 1 < T) ? se[tid + 1] : 0.0f;
    __syncthreads();

    // ---- local reverse scan: suffix_lse per slot, accumulate (lse - x) ----
    float Ms = Ms0, Es = Es0;
    float local = 0.0f;
    #pragma unroll
    for (int c = C - 1; c >= 0; --c) {
        const float xv = x[c];
        if (xv > Ms) { Es = Es * __expf(Ms - xv) + 1.0f; Ms = xv; }
        else         { Es += __expf(xv - Ms); }
        local += (Ms + __logf(Es)) - xv;
    }

    // ---- block reduction of local sums ----
    sm[tid] = local;
    __syncthreads();
    for (int off = T / 2; off > 0; off >>= 1) {
        if (tid < off) sm[tid] += sm[tid + off];
        __syncthreads();
    }
    if (tid == 0) row_loss[row] = sm[0];
}

__global__ __launch_bounds__(256) void listmle_reduce_kernel(
        const float* __restrict__ row_loss, float* __restrict__ out, int B) {
    __shared__ float s[256];
    float acc = 0.0f;
    for (int i = threadIdx.x; i < B; i += 256) acc += row_loss[i];
    s[threadIdx.x] = acc;
    __syncthreads();
    for (int off = 128; off > 0; off >>= 1) {
        if (threadIdx.x < off) s[threadIdx.x] += s[threadIdx.x + off];
        __syncthreads();
    }
    if (threadIdx.x == 0) out[0] = s[0] / (float)B;
}

extern "C" void kernel_launch(void* const* d_in, const int* in_sizes, int n_in,
                              void* d_out, int out_size, void* d_ws, size_t ws_size,
                              hipStream_t stream) {
    const float* scores = (const float*)d_in[0];
    const float* labels = (const float*)d_in[1];
    float* out = (float*)d_out;
    float* row_loss = (float*)d_ws;   // B floats of scratch

    const int B = in_sizes[0] / L;    // 8192

    listmle_row_kernel<<<B, T, 0, stream>>>(scores, labels, row_loss);
    listmle_reduce_kernel<<<1, 256, 0, stream>>>(row_loss, out, B);
}

// Round 2
// 238.559 us; speedup vs baseline: 1.4847x; 1.4847x over previous
//
#include <hip/hip_runtime.h>
#include <math.h>

// ListMLE loss: B=8192 rows, L=2048 cols.
// loss = mean_over_rows( sum_i [ LSE(s_sorted[i:]) - s_sorted[i] ] )
// where s_sorted = scores gathered by argsort(-labels) (stable).
//
// Sort strategy: register-resident bitonic sort, 8 elements/thread.
//   j in {1,2,4}   -> in-register compare-exchange (no LDS, no barrier)
//   j in {8..256}  -> __shfl_xor on 64-bit keys (partner lane = t ^ j/8)
//   j in {512,1024}-> 3 LDS exchange steps, XOR-swizzled (4-way = free for b64)

constexpr int L = 2048;
constexpr int T = 256;          // threads per block
constexpr int C = L / T;        // 8 elements per thread

// Order-preserving float32 -> uint32 transform (unsigned compare == float compare).
__device__ inline unsigned keyxform(float f) {
    unsigned u = __float_as_uint(f);
    return (u & 0x80000000u) ? ~u : (u | 0x80000000u);
}

// In-register compare-exchange; a is the lower index, desc => a keeps the larger.
__device__ inline void ce(unsigned long long& a, unsigned long long& b, bool desc) {
    const bool sw = desc ? (a < b) : (a > b);
    const unsigned long long t0 = a, t1 = b;
    a = sw ? t1 : t0;
    b = sw ? t0 : t1;
}

template<int M>
__device__ inline void shflStep(unsigned long long k[C], bool desc, int t) {
    const bool lower = ((t & M) == 0);
    const bool keepMax = (desc == lower);
    #pragma unroll
    for (int c = 0; c < C; ++c) {
        const unsigned long long o = __shfl_xor(k[c], M, 64);
        const bool take = keepMax ? (o > k[c]) : (o < k[c]);
        k[c] = take ? o : k[c];
    }
}

template<int M>
__device__ inline void shflCascade(unsigned long long k[C], bool desc, int t) {
    shflStep<M>(k, desc, t);
    if constexpr (M > 1) shflCascade<(M >> 1)>(k, desc, t);
}

// j = 4, 2, 1 within this thread's 8 elements, uniform direction.
__device__ inline void tail421(unsigned long long k[C], bool desc) {
    ce(k[0],k[4],desc); ce(k[1],k[5],desc); ce(k[2],k[6],desc); ce(k[3],k[7],desc);
    ce(k[0],k[2],desc); ce(k[1],k[3],desc); ce(k[4],k[6],desc); ce(k[5],k[7],desc);
    ce(k[0],k[1],desc); ce(k[2],k[3],desc); ce(k[4],k[5],desc); ce(k[6],k[7],desc);
}

// Bank-spreading bijection for the u64 key buffer (bank-pair = idx mod 16).
__device__ inline int swz(int p) { return p ^ ((p >> 4) & 15); }

__device__ inline void ldsStep(unsigned long long* kbuf, unsigned long long k[C],
                               int m, bool desc, int t) {
    #pragma unroll
    for (int c = 0; c < C; ++c) kbuf[swz(C * t + c)] = k[c];
    __syncthreads();
    const int pt = t ^ m;
    const bool lower = ((t & m) == 0);
    const bool keepMax = (desc == lower);
    #pragma unroll
    for (int c = 0; c < C; ++c) {
        const unsigned long long o = kbuf[swz(C * pt + c)];
        const bool take = keepMax ? (o > k[c]) : (o < k[c]);
        k[c] = take ? o : k[c];
    }
    __syncthreads();
}

__global__ __launch_bounds__(T) void listmle_row_kernel(
        const float* __restrict__ scores,
        const float* __restrict__ labels,
        float* __restrict__ row_loss) {
    __shared__ unsigned long long kbuf[L];  // 16 KB, used only for 3 exchange steps
    __shared__ float sc[L];                 // 8 KB
    __shared__ float sm[T];                 // 1 KB
    __shared__ float se[T];                 // 1 KB

    const int row = blockIdx.x;
    const int t = threadIdx.x;
    const long long base = (long long)row * L;

    // ---- load: thread t owns elements 8t..8t+7 ----
    unsigned long long k[C];
    {
        const float4 l0 = ((const float4*)(labels + base + C * t))[0];
        const float4 l1 = ((const float4*)(labels + base + C * t))[1];
        const float4 s0 = ((const float4*)(scores + base + C * t))[0];
        const float4 s1 = ((const float4*)(scores + base + C * t))[1];
        const float lv[C] = {l0.x,l0.y,l0.z,l0.w,l1.x,l1.y,l1.z,l1.w};
        const float sv[C] = {s0.x,s0.y,s0.z,s0.w,s1.x,s1.y,s1.z,s1.w};
        #pragma unroll
        for (int c = 0; c < C; ++c) {
            const int i = C * t + c;
            k[c] = ((unsigned long long)keyxform(lv[c]) << 32) | (unsigned)(~i);
            sc[i] = sv[c];
        }
    }
    // (barrier before the sc[] gather is provided by ldsStep barriers below)

    // ---- bitonic sort (descending), register/shuffle resident ----
    // k=2
    ce(k[0],k[1],true ); ce(k[2],k[3],false); ce(k[4],k[5],true ); ce(k[6],k[7],false);
    // k=4
    ce(k[0],k[2],true ); ce(k[1],k[3],true ); ce(k[4],k[6],false); ce(k[5],k[7],false);
    ce(k[0],k[1],true ); ce(k[2],k[3],true ); ce(k[4],k[5],false); ce(k[6],k[7],false);
    // k=8
    { const bool d = ((t & 1) == 0); tail421(k, d); }
    // k=16..512: shuffles + in-register tail
    { const bool d = ((t & 2)  == 0); shflCascade<1 >(k,d,t); tail421(k,d); }
    { const bool d = ((t & 4)  == 0); shflCascade<2 >(k,d,t); tail421(k,d); }
    { const bool d = ((t & 8)  == 0); shflCascade<4 >(k,d,t); tail421(k,d); }
    { const bool d = ((t & 16) == 0); shflCascade<8 >(k,d,t); tail421(k,d); }
    { const bool d = ((t & 32) == 0); shflCascade<16>(k,d,t); tail421(k,d); }
    { const bool d = ((t & 64) == 0); shflCascade<32>(k,d,t); tail421(k,d); }
    // k=1024: one cross-wave LDS step, then shuffles
    { const bool d = ((t & 128) == 0);
      ldsStep(kbuf,k,64,d,t); shflCascade<32>(k,d,t); tail421(k,d); }
    // k=2048: final descending merge
    { ldsStep(kbuf,k,128,true,t); ldsStep(kbuf,k,64,true,t);
      shflCascade<32>(k,true,t); tail421(k,true); }

    // ---- gather scores in sorted order ----
    float x[C];
    #pragma unroll
    for (int c = 0; c < C; ++c) {
        x[c] = sc[(int)(~(unsigned)k[c])];   // recover original column index
    }

    // ---- per-thread chunk LSE aggregate (m, e) with e = sum exp(x - m) ----
    float m = x[0], e = 1.0f;
    #pragma unroll
    for (int c = 1; c < C; ++c) {
        const float xv = x[c];
        if (xv > m) { e = e * __expf(m - xv) + 1.0f; m = xv; }
        else        { e += __expf(xv - m); }
    }

    // ---- inclusive suffix scan of (m, e) pairs across the 256 threads ----
    sm[t] = m;
    se[t] = e;
    __syncthreads();
    for (int off = 1; off < T; off <<= 1) {
        float m2 = -INFINITY, e2 = 0.0f;
        if (t + off < T) { m2 = sm[t + off]; e2 = se[t + off]; }
        __syncthreads();
        const float mm = sm[t], ee = se[t];
        const float M = fmaxf(mm, m2);
        const float E = ee * __expf(mm - M) + e2 * __expf(m2 - M);
        sm[t] = M;
        se[t] = E;
        __syncthreads();
    }

    // exclusive suffix aggregate for this thread = inclusive at t+1
    const float Ms0 = (t + 1 < T) ? sm[t + 1] : -INFINITY;
    const float Es0 = (t + 1 < T) ? se[t + 1] : 0.0f;
    __syncthreads();

    // ---- local reverse scan: suffix_lse per slot, accumulate (lse - x) ----
    float Ms = Ms0, Es = Es0;
    float local = 0.0f;
    #pragma unroll
    for (int c = C - 1; c >= 0; --c) {
        const float xv = x[c];
        if (xv > Ms) { Es = Es * __expf(Ms - xv) + 1.0f; Ms = xv; }
        else         { Es += __expf(xv - Ms); }
        local += (Ms + __logf(Es)) - xv;
    }

    // ---- block reduction of local sums ----
    sm[t] = local;
    __syncthreads();
    for (int off = T / 2; off > 0; off >>= 1) {
        if (t < off) sm[t] += sm[t + off];
        __syncthreads();
    }
    if (t == 0) row_loss[row] = sm[0];
}

__global__ __launch_bounds__(256) void listmle_reduce_kernel(
        const float* __restrict__ row_loss, float* __restrict__ out, int B) {
    __shared__ float s[256];
    float acc = 0.0f;
    for (int i = threadIdx.x; i < B; i += 256) acc += row_loss[i];
    s[threadIdx.x] = acc;
    __syncthreads();
    for (int off = 128; off > 0; off >>= 1) {
        if (threadIdx.x < off) s[threadIdx.x] += s[threadIdx.x + off];
        __syncthreads();
    }
    if (threadIdx.x == 0) out[0] = s[0] / (float)B;
}

extern "C" void kernel_launch(void* const* d_in, const int* in_sizes, int n_in,
                              void* d_out, int out_size, void* d_ws, size_t ws_size,
                              hipStream_t stream) {
    const float* scores = (const float*)d_in[0];
    const float* labels = (const float*)d_in[1];
    float* out = (float*)d_out;
    float* row_loss = (float*)d_ws;   // B floats of scratch

    const int B = in_sizes[0] / L;    // 8192

    listmle_row_kernel<<<B, T, 0, stream>>>(scores, labels, row_loss);
    listmle_reduce_kernel<<<1, 256, 0, stream>>>(row_loss, out, B);
}

// Round 3
// 107.965 us; speedup vs baseline: 3.2807x; 2.2096x over previous
//
#include <hip/hip_runtime.h>
#include <math.h>

// ListMLE loss: B=8192 rows, L=2048 cols.
// loss = mean_over_rows( sum_i [ LSE(s_sorted[i:]) - s_sorted[i] ] )
// where s_sorted = scores gathered by argsort(-labels) (stable).
//
// Sort: register-resident bitonic on 32-bit keys, 8 elems/thread.
//   key = (label_fix21 << 11) | (2047 - idx)   (descending sort => label desc, idx asc)
//   Direction-uniform trick: keys live in "stage space" key^F_k(i), F_k(i)=-(bit log2(k) of i),
//   so EVERY comparator is "lower index keeps max" (v_max_u32/v_min_u32).
//   masks 1..16 -> ds_swizzle imm; mask 32 -> ds_bpermute (precomputed addr);
//   masks 64/128 -> LDS exchange with XOR-swizzled layout.

constexpr int L = 2048;
constexpr int T = 256;          // threads per block
constexpr int C = 8;            // elements per thread

__device__ inline void CE(unsigned& a, unsigned& b) {   // lower keeps max
    const unsigned mx = a > b ? a : b;
    const unsigned mn = a > b ? b : a;
    a = mx; b = mn;
}

__device__ inline void tailU(unsigned k[C]) {           // j = 4,2,1 within thread
    CE(k[0],k[4]); CE(k[1],k[5]); CE(k[2],k[6]); CE(k[3],k[7]);
    CE(k[0],k[2]); CE(k[1],k[3]); CE(k[4],k[6]); CE(k[5],k[7]);
    CE(k[0],k[1]); CE(k[2],k[3]); CE(k[4],k[5]); CE(k[6],k[7]);
}

// Cross-lane exchange via ds_swizzle immediate XOR pattern (masks 1..16).
template<int PAT>
__device__ inline void swzStep(unsigned k[C], bool up) {
    #pragma unroll
    for (int c = 0; c < C; ++c) {
        const unsigned o = (unsigned)__builtin_amdgcn_ds_swizzle((int)k[c], PAT);
        const unsigned mx = k[c] > o ? k[c] : o;
        const unsigned mn = k[c] > o ? o : k[c];
        k[c] = up ? mn : mx;
    }
}

// mask 32 exchange via ds_bpermute (crosses the 32-lane swizzle boundary).
__device__ inline void bpStep(unsigned k[C], int bpa, bool up) {
    #pragma unroll
    for (int c = 0; c < C; ++c) {
        const unsigned o = (unsigned)__builtin_amdgcn_ds_bpermute(bpa, (int)k[c]);
        const unsigned mx = k[c] > o ? k[c] : o;
        const unsigned mn = k[c] > o ? o : k[c];
        k[c] = up ? mn : mx;
    }
}

__device__ inline void flipAll(unsigned k[C], unsigned d) {
    #pragma unroll
    for (int c = 0; c < C; ++c) k[c] ^= d;
}

// Cross-wave exchange through LDS (partner thread t^m, m in {64,128}).
__device__ inline void ldsStep(unsigned* kbuf, unsigned k[C], int m, int t, int tl, bool up) {
    const int wbase = C * t;
    #pragma unroll
    for (int c = 0; c < C; ++c) kbuf[wbase + (c ^ tl)] = k[c];
    __syncthreads();
    const int rbase = C * (t ^ m);   // (t^m)&7 == t&7, so same tl swizzle
    #pragma unroll
    for (int c = 0; c < C; ++c) {
        const unsigned o = kbuf[rbase + (c ^ tl)];
        const unsigned mx = k[c] > o ? k[c] : o;
        const unsigned mn = k[c] > o ? o : k[c];
        k[c] = up ? mn : mx;
    }
    __syncthreads();
}

__global__ __launch_bounds__(T) void listmle_row_kernel(
        const float* __restrict__ scores,
        const float* __restrict__ labels,
        float* __restrict__ row_loss) {
    __shared__ unsigned kbuf[L];    // 8 KB (only for the 3 cross-wave steps)
    __shared__ float sc[L];         // 8 KB, XOR-swizzled layout
    __shared__ float sm[T];         // 1 KB
    __shared__ float se[T];         // 1 KB

    const int row = blockIdx.x;
    const int t = threadIdx.x;
    const int tl = t & 7;
    const int lane = t & 63;
    const int bpa = (lane ^ 32) << 2;      // bpermute byte address, computed once
    const long long base = (long long)row * L;

    // ---- load: thread t owns elements 8t..8t+7; build keys directly in F2 space ----
    unsigned k[C];
    {
        const float4 l0 = ((const float4*)(labels + base + C * t))[0];
        const float4 l1 = ((const float4*)(labels + base + C * t))[1];
        const float4 s0 = ((const float4*)(scores + base + C * t))[0];
        const float4 s1 = ((const float4*)(scores + base + C * t))[1];
        const float lv[C] = {l0.x,l0.y,l0.z,l0.w,l1.x,l1.y,l1.z,l1.w};
        const float sv[C] = {s0.x,s0.y,s0.z,s0.w,s1.x,s1.y,s1.z,s1.w};
        const int baser = 2047 - C * t;
        #pragma unroll
        for (int c = 0; c < C; ++c) {
            const unsigned q = (unsigned)(lv[c] * 2097152.0f);        // 21-bit fixed point
            unsigned key = (q << 11) | (unsigned)(baser - c);
            if (c == 2 || c == 3 || c == 6 || c == 7) key = ~key;     // F2 space
            k[c] = key;
            sc[C * t + (c ^ tl)] = sv[c];                             // swizzled score store
        }
    }

    // ---- bitonic sort (descending), all comparators "lower keeps max" ----
    // k=2
    CE(k[0],k[1]); CE(k[2],k[3]); CE(k[4],k[5]); CE(k[6],k[7]);
    // F2 -> F4: flip slots 2,3,4,5
    k[2] = ~k[2]; k[3] = ~k[3]; k[4] = ~k[4]; k[5] = ~k[5];
    // k=4
    CE(k[0],k[2]); CE(k[1],k[3]); CE(k[4],k[6]); CE(k[5],k[7]);
    CE(k[0],k[1]); CE(k[2],k[3]); CE(k[4],k[5]); CE(k[6],k[7]);
    // F4 -> F8
    { const unsigned m = (unsigned)(-(int)(t & 1));
      k[0]^=m; k[1]^=m; k[2]^=m; k[3]^=m;
      k[4]^=~m; k[5]^=~m; k[6]^=~m; k[7]^=~m; }
    // k=8
    tailU(k);
    // k=16
    flipAll(k, (unsigned)(-(int)((t ^ (t>>1)) & 1)));
    swzStep<0x041F>(k, (t & 1) != 0);
    tailU(k);
    // k=32
    flipAll(k, (unsigned)(-(int)(((t>>1) ^ (t>>2)) & 1)));
    swzStep<0x081F>(k, (t & 2) != 0);
    swzStep<0x041F>(k, (t & 1) != 0);
    tailU(k);
    // k=64
    flipAll(k, (unsigned)(-(int)(((t>>2) ^ (t>>3)) & 1)));
    swzStep<0x101F>(k, (t & 4) != 0);
    swzStep<0x081F>(k, (t & 2) != 0);
    swzStep<0x041F>(k, (t & 1) != 0);
    tailU(k);
    // k=128
    flipAll(k, (unsigned)(-(int)(((t>>3) ^ (t>>4)) & 1)));
    swzStep<0x201F>(k, (t & 8) != 0);
    swzStep<0x101F>(k, (t & 4) != 0);
    swzStep<0x081F>(k, (t & 2) != 0);
    swzStep<0x041F>(k, (t & 1) != 0);
    tailU(k);
    // k=256
    flipAll(k, (unsigned)(-(int)(((t>>4) ^ (t>>5)) & 1)));
    swzStep<0x401F>(k, (t & 16) != 0);
    swzStep<0x201F>(k, (t & 8) != 0);
    swzStep<0x101F>(k, (t & 4) != 0);
    swzStep<0x081F>(k, (t & 2) != 0);
    swzStep<0x041F>(k, (t & 1) != 0);
    tailU(k);
    // k=512
    flipAll(k, (unsigned)(-(int)(((t>>5) ^ (t>>6)) & 1)));
    bpStep(k, bpa, (t & 32) != 0);
    swzStep<0x401F>(k, (t & 16) != 0);
    swzStep<0x201F>(k, (t & 8) != 0);
    swzStep<0x101F>(k, (t & 4) != 0);
    swzStep<0x081F>(k, (t & 2) != 0);
    swzStep<0x041F>(k, (t & 1) != 0);
    tailU(k);
    // k=1024
    flipAll(k, (unsigned)(-(int)(((t>>6) ^ (t>>7)) & 1)));
    ldsStep(kbuf, k, 64, t, tl, (t & 64) != 0);
    bpStep(k, bpa, (t & 32) != 0);
    swzStep<0x401F>(k, (t & 16) != 0);
    swzStep<0x201F>(k, (t & 8) != 0);
    swzStep<0x101F>(k, (t & 4) != 0);
    swzStep<0x081F>(k, (t & 2) != 0);
    swzStep<0x041F>(k, (t & 1) != 0);
    tailU(k);
    // k=2048 (final, F=0 -> keys back to raw space)
    flipAll(k, (unsigned)(-(int)((t>>7) & 1)));
    ldsStep(kbuf, k, 128, t, tl, (t & 128) != 0);
    ldsStep(kbuf, k, 64,  t, tl, (t & 64)  != 0);
    bpStep(k, bpa, (t & 32) != 0);
    swzStep<0x401F>(k, (t & 16) != 0);
    swzStep<0x201F>(k, (t & 8) != 0);
    swzStep<0x101F>(k, (t & 4) != 0);
    swzStep<0x081F>(k, (t & 2) != 0);
    swzStep<0x041F>(k, (t & 1) != 0);
    tailU(k);

    // ---- gather scores in sorted order (sc is swizzled) ----
    float x[C];
    #pragma unroll
    for (int c = 0; c < C; ++c) {
        const int idx = 2047 - (int)(k[c] & 2047u);
        x[c] = sc[(idx & ~7) | ((idx ^ (idx >> 3)) & 7)];
    }

    // ---- per-thread chunk LSE aggregate (m, e), branchless ----
    float m = x[0], e = 1.0f;
    #pragma unroll
    for (int c = 1; c < C; ++c) {
        const float nm = fmaxf(m, x[c]);
        e = e * __expf(m - nm) + __expf(x[c] - nm);
        m = nm;
    }

    // ---- inclusive suffix scan of (m, e) pairs across the 256 threads ----
    sm[t] = m;
    se[t] = e;
    __syncthreads();
    for (int off = 1; off < T; off <<= 1) {
        float m2 = -INFINITY, e2 = 0.0f;
        if (t + off < T) { m2 = sm[t + off]; e2 = se[t + off]; }
        __syncthreads();
        const float mm = sm[t], ee = se[t];
        const float M = fmaxf(mm, m2);
        const float E = ee * __expf(mm - M) + e2 * __expf(m2 - M);
        sm[t] = M;
        se[t] = E;
        __syncthreads();
    }

    // exclusive suffix aggregate for this thread = inclusive at t+1
    const float Ms0 = (t + 1 < T) ? sm[t + 1] : -INFINITY;
    const float Es0 = (t + 1 < T) ? se[t + 1] : 0.0f;
    __syncthreads();

    // ---- local reverse scan: suffix_lse per slot, accumulate (lse - x) ----
    float Ms = Ms0, Es = Es0;
    float local = 0.0f;
    #pragma unroll
    for (int c = C - 1; c >= 0; --c) {
        const float nm = fmaxf(Ms, x[c]);
        Es = Es * __expf(Ms - nm) + __expf(x[c] - nm);
        Ms = nm;
        local += (Ms + __logf(Es)) - x[c];
    }

    // ---- block reduction of local sums ----
    sm[t] = local;
    __syncthreads();
    for (int off = T / 2; off > 0; off >>= 1) {
        if (t < off) sm[t] += sm[t + off];
        __syncthreads();
    }
    if (t == 0) row_loss[row] = sm[0];
}

__global__ __launch_bounds__(256) void listmle_reduce_kernel(
        const float* __restrict__ row_loss, float* __restrict__ out, int B) {
    __shared__ float s[256];
    float acc = 0.0f;
    for (int i = threadIdx.x; i < B; i += 256) acc += row_loss[i];
    s[threadIdx.x] = acc;
    __syncthreads();
    for (int off = 128; off > 0; off >>= 1) {
        if (threadIdx.x < off) s[threadIdx.x] += s[threadIdx.x + off];
        __syncthreads();
    }
    if (threadIdx.x == 0) out[0] = s[0] / (float)B;
}

extern "C" void kernel_launch(void* const* d_in, const int* in_sizes, int n_in,
                              void* d_out, int out_size, void* d_ws, size_t ws_size,
                              hipStream_t stream) {
    const float* scores = (const float*)d_in[0];
    const float* labels = (const float*)d_in[1];
    float* out = (float*)d_out;
    float* row_loss = (float*)d_ws;   // B floats of scratch

    const int B = in_sizes[0] / L;    // 8192

    listmle_row_kernel<<<B, T, 0, stream>>>(scores, labels, row_loss);
    listmle_reduce_kernel<<<1, 256, 0, stream>>>(row_loss, out, B);
}

// Round 4
// 83.923 us; speedup vs baseline: 4.2205x; 1.2865x over previous
//
#include <hip/hip_runtime.h>
#include <math.h>

// ListMLE loss: B=8192 rows, L=2048 cols.
// loss = mean_over_rows( sum_i [ LSE(s_sorted[i:]) - s_sorted[i] ] )
// where s_sorted = scores gathered by argsort(-labels) (stable).
//
// Key insight this version: fuse the (quantized) score into the sort key.
//   key = (label_q21 << 11) | score_q11
// After the descending bitonic sort, the low 11 bits ARE the score at that
// sorted position -> no score array in LDS, no gather, no index recovery.
// Sum(s) is computed exactly from the raw loads (order-independent).
//
// Sort: register-resident bitonic on 32-bit keys, 8 elems/thread.
//   Stage-space flips (flipAll) keep in-register comparators direction-free;
//   cross-lane exchanges use ((k>o) != up) select (cmp + cndmask, role-xor
//   folds to SALU). masks 1..16 -> ds_swizzle imm; 32 -> ds_bpermute;
//   64/128 -> LDS round-trip with uint4 vector ops.

constexpr int L = 2048;
constexpr int T = 256;          // threads per block
constexpr int C = 8;            // elements per thread

__device__ inline void CE(unsigned& a, unsigned& b) {   // lower keeps max
    const unsigned mx = a > b ? a : b;
    const unsigned mn = a > b ? b : a;
    a = mx; b = mn;
}

__device__ inline void tailU(unsigned k[C]) {           // j = 4,2,1 within thread
    CE(k[0],k[4]); CE(k[1],k[5]); CE(k[2],k[6]); CE(k[3],k[7]);
    CE(k[0],k[2]); CE(k[1],k[3]); CE(k[4],k[6]); CE(k[5],k[7]);
    CE(k[0],k[1]); CE(k[2],k[3]); CE(k[4],k[5]); CE(k[6],k[7]);
}

// Cross-lane exchange via ds_swizzle immediate XOR pattern (lane masks 1..16).
template<int PAT, int M>
__device__ inline void swzStep(unsigned k[C], int t) {
    const bool up = (t & M) != 0;
    #pragma unroll
    for (int c = 0; c < C; ++c) {
        const unsigned o = (unsigned)__builtin_amdgcn_ds_swizzle((int)k[c], PAT);
        k[c] = ((k[c] > o) != up) ? k[c] : o;
    }
}

// Lane-mask 32 exchange via ds_bpermute (crosses the 32-lane swizzle limit).
__device__ inline void bpStep(unsigned k[C], int bpa, int t) {
    const bool up = (t & 32) != 0;
    #pragma unroll
    for (int c = 0; c < C; ++c) {
        const unsigned o = (unsigned)__builtin_amdgcn_ds_bpermute(bpa, (int)k[c]);
        k[c] = ((k[c] > o) != up) ? k[c] : o;
    }
}

__device__ inline void flipAll(unsigned k[C], unsigned d) {
    #pragma unroll
    for (int c = 0; c < C; ++c) k[c] ^= d;
}

// Cross-wave exchange through LDS (partner thread t^m, m in {64,128}).
__device__ inline void ldsStep(uint4* kb4, unsigned k[C], int m, int t) {
    kb4[2 * t]     = make_uint4(k[0], k[1], k[2], k[3]);
    kb4[2 * t + 1] = make_uint4(k[4], k[5], k[6], k[7]);
    __syncthreads();
    const int pb = (t ^ m) << 1;
    const uint4 a = kb4[pb];
    const uint4 b = kb4[pb + 1];
    const unsigned o[C] = {a.x, a.y, a.z, a.w, b.x, b.y, b.z, b.w};
    const bool up = (t & m) != 0;
    #pragma unroll
    for (int c = 0; c < C; ++c) {
        k[c] = ((k[c] > o[c]) != up) ? k[c] : o[c];
    }
    __syncthreads();
}

__device__ inline float bperm_f(int addr, float v) {
    return __uint_as_float((unsigned)__builtin_amdgcn_ds_bpermute(addr, (int)__float_as_uint(v)));
}

__global__ __launch_bounds__(T) void listmle_row_kernel(
        const float* __restrict__ scores,
        const float* __restrict__ labels,
        float* __restrict__ row_loss) {
    __shared__ uint4 kb4[L / 4];    // 8 KB (3 cross-wave exchange steps)
    __shared__ float smw[4], sew[4];
    __shared__ float red[4];

    const int row = blockIdx.x;
    const int t = threadIdx.x;
    const int lane = t & 63;
    const int w = t >> 6;
    const int la4 = lane << 2;
    const int bpa = (lane ^ 32) << 2;      // bpermute byte addr for lane^32
    const long long base = (long long)row * L;

    // ---- load: thread t owns elements 8t..8t+7; build fused keys in F2 space ----
    unsigned k[C];
    float acc_s;
    {
        const float4* lp = (const float4*)(labels + base + C * t);
        const float4* sp = (const float4*)(scores + base + C * t);
        const float4 l0 = lp[0], l1 = lp[1];
        const float4 s0 = sp[0], s1 = sp[1];
        const float lv[C] = {l0.x,l0.y,l0.z,l0.w,l1.x,l1.y,l1.z,l1.w};
        const float sv[C] = {s0.x,s0.y,s0.z,s0.w,s1.x,s1.y,s1.z,s1.w};
        acc_s = ((s0.x + s0.y) + (s0.z + s0.w)) + ((s1.x + s1.y) + (s1.z + s1.w));
        #pragma unroll
        for (int c = 0; c < C; ++c) {
            const unsigned ql = (unsigned)(lv[c] * 2097152.0f);       // 21-bit label
            const float qsf = fminf(fmaxf(fmaf(sv[c], 128.0f, 1024.5f), 0.0f), 2047.0f);
            unsigned key = (ql << 11) | (unsigned)qsf;                // 11-bit score
            if (c == 2 || c == 3 || c == 6 || c == 7) key = ~key;     // F2 space
            k[c] = key;
        }
    }

    // ---- bitonic sort (descending) ----
    // k=2
    CE(k[0],k[1]); CE(k[2],k[3]); CE(k[4],k[5]); CE(k[6],k[7]);
    // F2 -> F4
    k[2] = ~k[2]; k[3] = ~k[3]; k[4] = ~k[4]; k[5] = ~k[5];
    // k=4
    CE(k[0],k[2]); CE(k[1],k[3]); CE(k[4],k[6]); CE(k[5],k[7]);
    CE(k[0],k[1]); CE(k[2],k[3]); CE(k[4],k[5]); CE(k[6],k[7]);
    // F4 -> F8
    { const unsigned m = (unsigned)(-(int)(t & 1));
      k[0]^=m; k[1]^=m; k[2]^=m; k[3]^=m;
      k[4]^=~m; k[5]^=~m; k[6]^=~m; k[7]^=~m; }
    // k=8
    tailU(k);
    // k=16
    flipAll(k, (unsigned)(-(int)((t ^ (t>>1)) & 1)));
    swzStep<0x041F,1>(k, t);
    tailU(k);
    // k=32
    flipAll(k, (unsigned)(-(int)(((t>>1) ^ (t>>2)) & 1)));
    swzStep<0x081F,2>(k, t);
    swzStep<0x041F,1>(k, t);
    tailU(k);
    // k=64
    flipAll(k, (unsigned)(-(int)(((t>>2) ^ (t>>3)) & 1)));
    swzStep<0x101F,4>(k, t);
    swzStep<0x081F,2>(k, t);
    swzStep<0x041F,1>(k, t);
    tailU(k);
    // k=128
    flipAll(k, (unsigned)(-(int)(((t>>3) ^ (t>>4)) & 1)));
    swzStep<0x201F,8>(k, t);
    swzStep<0x101F,4>(k, t);
    swzStep<0x081F,2>(k, t);
    swzStep<0x041F,1>(k, t);
    tailU(k);
    // k=256
    flipAll(k, (unsigned)(-(int)(((t>>4) ^ (t>>5)) & 1)));
    swzStep<0x401F,16>(k, t);
    swzStep<0x201F,8>(k, t);
    swzStep<0x101F,4>(k, t);
    swzStep<0x081F,2>(k, t);
    swzStep<0x041F,1>(k, t);
    tailU(k);
    // k=512
    flipAll(k, (unsigned)(-(int)(((t>>5) ^ (t>>6)) & 1)));
    bpStep(k, bpa, t);
    swzStep<0x401F,16>(k, t);
    swzStep<0x201F,8>(k, t);
    swzStep<0x101F,4>(k, t);
    swzStep<0x081F,2>(k, t);
    swzStep<0x041F,1>(k, t);
    tailU(k);
    // k=1024
    flipAll(k, (unsigned)(-(int)(((t>>6) ^ (t>>7)) & 1)));
    ldsStep(kb4, k, 64, t);
    bpStep(k, bpa, t);
    swzStep<0x401F,16>(k, t);
    swzStep<0x201F,8>(k, t);
    swzStep<0x101F,4>(k, t);
    swzStep<0x081F,2>(k, t);
    swzStep<0x041F,1>(k, t);
    tailU(k);
    // k=2048 (final descending merge, F = 0)
    flipAll(k, (unsigned)(-(int)((t>>7) & 1)));
    ldsStep(kb4, k, 128, t);
    ldsStep(kb4, k, 64, t);
    bpStep(k, bpa, t);
    swzStep<0x401F,16>(k, t);
    swzStep<0x201F,8>(k, t);
    swzStep<0x101F,4>(k, t);
    swzStep<0x081F,2>(k, t);
    swzStep<0x041F,1>(k, t);
    tailU(k);

    // ---- dequantize sorted scores from key low bits ----
    float x[C];
    #pragma unroll
    for (int c = 0; c < C; ++c) {
        x[c] = fmaf((float)(k[c] & 2047u), 0.0078125f, -8.0f);
    }

    // ---- per-thread chunk LSE aggregate: max tree + independent exps ----
    float m = fmaxf(fmaxf(fmaxf(x[0], x[1]), fmaxf(x[2], x[3])),
                    fmaxf(fmaxf(x[4], x[5]), fmaxf(x[6], x[7])));
    float e = 0.0f;
    #pragma unroll
    for (int c = 0; c < C; ++c) e += __expf(x[c] - m);

    // ---- wave-level inclusive suffix scan of (m, e) via bpermute ----
    #pragma unroll
    for (int off = 1; off < 64; off <<= 1) {
        const int a = la4 + (off << 2);
        float m2 = bperm_f(a, m);
        float e2 = bperm_f(a, e);
        const bool valid = (lane + off) < 64;
        m2 = valid ? m2 : -INFINITY;
        e2 = valid ? e2 : 0.0f;
        const float M = fmaxf(m, m2);
        e = e * __expf(m - M) + e2 * __expf(m2 - M);
        m = M;
    }

    // exclusive-within-wave suffix for this thread
    float Ms, Es;
    {
        const int a = la4 + 4;
        const float me = bperm_f(a, m);
        const float ee = bperm_f(a, e);
        const bool v = lane < 63;
        Ms = v ? me : -INFINITY;
        Es = v ? ee : 0.0f;
    }

    // ---- cross-wave: combine aggregates of higher waves ----
    if (lane == 0) { smw[w] = m; sew[w] = e; }
    __syncthreads();
    #pragma unroll
    for (int d = 1; d < 4; ++d) {
        if (w + d < 4) {
            const float m2 = smw[w + d], e2 = sew[w + d];
            const float M = fmaxf(Ms, m2);
            Es = Es * __expf(Ms - M) + e2 * __expf(m2 - M);
            Ms = M;
        }
    }

    // ---- local reverse scan: suffix_lse per slot ----
    float lsum = 0.0f;
    #pragma unroll
    for (int c = C - 1; c >= 0; --c) {
        const float nm = fmaxf(Ms, x[c]);
        Es = Es * __expf(Ms - nm) + __expf(x[c] - nm);
        Ms = nm;
        lsum += nm + __logf(Es);
    }

    // ---- reduce (lsum - exact score sum) across the block ----
    float v = lsum - acc_s;
    v += __uint_as_float((unsigned)__builtin_amdgcn_ds_swizzle((int)__float_as_uint(v), 0x041F));
    v += __uint_as_float((unsigned)__builtin_amdgcn_ds_swizzle((int)__float_as_uint(v), 0x081F));
    v += __uint_as_float((unsigned)__builtin_amdgcn_ds_swizzle((int)__float_as_uint(v), 0x101F));
    v += __uint_as_float((unsigned)__builtin_amdgcn_ds_swizzle((int)__float_as_uint(v), 0x201F));
    v += __uint_as_float((unsigned)__builtin_amdgcn_ds_swizzle((int)__float_as_uint(v), 0x401F));
    v += bperm_f(bpa, v);
    if (lane == 0) red[w] = v;
    __syncthreads();
    if (t == 0) row_loss[row] = (red[0] + red[1]) + (red[2] + red[3]);
}

__global__ __launch_bounds__(256) void listmle_reduce_kernel(
        const float* __restrict__ row_loss, float* __restrict__ out, int B) {
    __shared__ float s[256];
    float acc = 0.0f;
    for (int i = threadIdx.x; i < B; i += 256) acc += row_loss[i];
    s[threadIdx.x] = acc;
    __syncthreads();
    for (int off = 128; off > 0; off >>= 1) {
        if (threadIdx.x < off) s[threadIdx.x] += s[threadIdx.x + off];
        __syncthreads();
    }
    if (threadIdx.x == 0) out[0] = s[0] / (float)B;
}

extern "C" void kernel_launch(void* const* d_in, const int* in_sizes, int n_in,
                              void* d_out, int out_size, void* d_ws, size_t ws_size,
                              hipStream_t stream) {
    const float* scores = (const float*)d_in[0];
    const float* labels = (const float*)d_in[1];
    float* out = (float*)d_out;
    float* row_loss = (float*)d_ws;   // B floats of scratch

    const int B = in_sizes[0] / L;    // 8192

    listmle_row_kernel<<<B, T, 0, stream>>>(scores, labels, row_loss);
    listmle_reduce_kernel<<<1, 256, 0, stream>>>(row_loss, out, B);
}